// Round 2
// baseline (16283.611 us; speedup 1.0000x reference)
//
#include <hip/hip_runtime.h>

#define Bz 64
#define Sz 512
#define Iz 512
#define Hz 1024
#define Lz 6
#define NLWG 96
#define NXWG 16
#define NB 112

typedef __attribute__((ext_vector_type(8))) short bf16x8;
typedef __attribute__((ext_vector_type(4))) float f32x4;

__device__ __forceinline__ unsigned short f2bf(float f) {
  unsigned u = __float_as_uint(f);
  u += 0x7fffu + ((u >> 16) & 1u);
  return (unsigned short)(u >> 16);
}

// add two packed bf16 pairs in f32, RNE back to packed bf16
__device__ __forceinline__ unsigned bfadd2(unsigned a, unsigned b) {
  float alo = __uint_as_float(a << 16);
  float ahi = __uint_as_float(a & 0xffff0000u);
  float blo = __uint_as_float(b << 16);
  float bhi = __uint_as_float(b & 0xffff0000u);
  float lo = alo + blo;
  float hi = ahi + bhi;
  unsigned ul = __float_as_uint(lo);
  ul += 0x7fffu + ((ul >> 16) & 1u);
  unsigned uh = __float_as_uint(hi);
  uh += 0x7fffu + ((uh >> 16) & 1u);
  return (ul >> 16) | (uh & 0xffff0000u);
}

// pack two f32 -> bf16 pair, round-half-up (cheap, unbiased enough for MFMA input)
__device__ __forceinline__ unsigned pkrnd(float lo, float hi) {
  return ((__float_as_uint(lo) + 0x8000u) >> 16) |
         ((__float_as_uint(hi) + 0x8000u) & 0xffff0000u);
}

__global__ void init_kernel(const float* __restrict__ bih, const float* __restrict__ bhh,
                            const float* __restrict__ bout,
                            unsigned int* __restrict__ hbuf32,
                            float* __restrict__ bias0, float* __restrict__ bias1,
                            float* __restrict__ out, int* __restrict__ cnt) {
  int tid = blockIdx.x * blockDim.x + threadIdx.x;
  int nt = gridDim.x * blockDim.x;
  for (int i = tid; i < (2 * Lz * Bz * Hz) / 2; i += nt) hbuf32[i] = 0u;
  for (int i = tid; i < Hz; i += nt) {
    bias0[i] = bih[i] + bhh[i];   // layer 0
    bias1[i] = 2.0f * bhh[i];     // layers 1..5 (bias added twice in ref)
  }
  float b0 = bout[0];
  for (int i = tid; i < Bz * Sz; i += nt) out[i] = b0;
  if (tid == 0) *cnt = 0;
}

// Persistent wavefront kernel.
// Blocks 0..95: (layer = bid>>4, ntile = bid&15); 64x64 output tile, K=1024, W_hh slice LDS-resident.
// Blocks 96..111: xproj crew; computes xproj[t+2] = x_{t+2} @ W_ih^T into f32 ring, W_ih slice LDS-resident.
__global__ __launch_bounds__(256, 1) void rnn_kernel(
    const float* __restrict__ x, const float* __restrict__ wih,
    const float* __restrict__ whh, const float* __restrict__ wout,
    unsigned short* __restrict__ hbuf, float* __restrict__ xq,
    const float* __restrict__ bias0, const float* __restrict__ bias1,
    float* __restrict__ dout, int* __restrict__ cnt) {
  extern __shared__ char lds[];
  unsigned short* Wlds = (unsigned short*)lds;                   // [64][Kw] swizzled
  unsigned short* Abuf = (unsigned short*)(lds + 131072);        // 2 x [64][64]

  const int bid = blockIdx.x;
  const int tid = threadIdx.x;
  const bool isx = (bid >= NLWG);
  const int layer = isx ? 0 : (bid >> 4);
  const int c0 = (isx ? (bid - NLWG) : (bid & 15)) << 6;
  const int Kw = isx ? Iz : Hz;
  const float* wsrc = isx ? wih : whh;

  // ---- one-time: stage W slice f32 -> bf16, XOR-swizzled
  for (int idx = tid; idx < (64 * Kw) >> 3; idx += 256) {
    const int row = idx / (Kw >> 3);
    const int kg = (idx % (Kw >> 3)) << 3;
    const float* sp = wsrc + (size_t)(c0 + row) * Kw + kg;
    float4 f0 = *(const float4*)sp;
    float4 f1 = *(const float4*)(sp + 4);
    uint4 v;
    v.x = (unsigned)f2bf(f0.x) | ((unsigned)f2bf(f0.y) << 16);
    v.y = (unsigned)f2bf(f0.z) | ((unsigned)f2bf(f0.w) << 16);
    v.z = (unsigned)f2bf(f1.x) | ((unsigned)f2bf(f1.y) << 16);
    v.w = (unsigned)f2bf(f1.z) | ((unsigned)f2bf(f1.w) << 16);
    *(uint4*)&Wlds[row * Kw + (kg ^ ((row & 7) << 3))] = v;
  }
  __syncthreads();

  const int lane = tid & 63;
  const int wav = tid >> 6;
  const int cc = lane & 15;
  const int gg = lane >> 4;
  const int sr = tid >> 2;
  const int skq = (tid & 3) << 4;
  const int wrow = wav * 16 + cc;        // output col within tile
  const int xw = (wrow & 7) << 3;
  const int swz0 = skq ^ ((sr & 7) << 3);
  const int swz1 = (skq + 8) ^ ((sr & 7) << 3);

  for (int w = -2; w <= Sz + Lz - 2; ++w) {
    if (!isx) {
      const int t = w - layer;
      if (t >= 0 && t < Sz) {
        const unsigned short* hrd = hbuf + (size_t)(w & 1) * (Lz * Bz * Hz);
        unsigned short* hwr = hbuf + (size_t)((w + 1) & 1) * (Lz * Bz * Hz);
        const unsigned short* sA =
            hrd + ((size_t)(layer > 0 ? layer - 1 : 0) * Bz + sr) * Hz + skq;
        const unsigned short* sB = hrd + ((size_t)layer * Bz + sr) * Hz + skq;

        f32x4 acc[4];
#pragma unroll
        for (int m = 0; m < 4; ++m) acc[m] = (f32x4){0.f, 0.f, 0.f, 0.f};

        uint4 rA[2][2], rB[2][2];
        rA[0][0] = *(const uint4*)(sA);
        rA[0][1] = *(const uint4*)(sA + 8);
        if (layer > 0) {
          rB[0][0] = *(const uint4*)(sB);
          rB[0][1] = *(const uint4*)(sB + 8);
        }
#pragma unroll 2
        for (int step = 0; step < 16; ++step) {
          const int cur = step & 1;
          uint4 w0, w1;
          if (layer > 0) {
            w0.x = bfadd2(rA[cur][0].x, rB[cur][0].x);
            w0.y = bfadd2(rA[cur][0].y, rB[cur][0].y);
            w0.z = bfadd2(rA[cur][0].z, rB[cur][0].z);
            w0.w = bfadd2(rA[cur][0].w, rB[cur][0].w);
            w1.x = bfadd2(rA[cur][1].x, rB[cur][1].x);
            w1.y = bfadd2(rA[cur][1].y, rB[cur][1].y);
            w1.z = bfadd2(rA[cur][1].z, rB[cur][1].z);
            w1.w = bfadd2(rA[cur][1].w, rB[cur][1].w);
          } else {
            w0 = rA[cur][0];
            w1 = rA[cur][1];
          }
          unsigned short* ab = &Abuf[cur * 4096];
          *(uint4*)&ab[sr * 64 + swz0] = w0;
          *(uint4*)&ab[sr * 64 + swz1] = w1;
          if (step < 15) {  // issue next-chunk loads BEFORE barrier; no vmcnt drain
            const int kk = (step + 1) * 64;
            rA[cur ^ 1][0] = *(const uint4*)(sA + kk);
            rA[cur ^ 1][1] = *(const uint4*)(sA + kk + 8);
            if (layer > 0) {
              rB[cur ^ 1][0] = *(const uint4*)(sB + kk);
              rB[cur ^ 1][1] = *(const uint4*)(sB + kk + 8);
            }
          }
          asm volatile("s_waitcnt lgkmcnt(0)" ::: "memory");
          __builtin_amdgcn_s_barrier();
          asm volatile("" ::: "memory");
#pragma unroll
          for (int ks = 0; ks < 2; ++ks) {
            const int k8g = step * 64 + ks * 32 + gg * 8;
            const bf16x8 bfrag = *(const bf16x8*)&Wlds[wrow * Hz + (k8g ^ xw)];
            const int kl = ks * 32 + gg * 8;
#pragma unroll
            for (int m = 0; m < 4; ++m) {
              const int ra = m * 16 + cc;
              const bf16x8 afrag =
                  *(const bf16x8*)&ab[ra * 64 + (kl ^ ((ra & 7) << 3))];
              acc[m] = __builtin_amdgcn_mfma_f32_16x16x32_bf16(afrag, bfrag, acc[m], 0, 0, 0);
            }
          }
        }

        // ---- epilogue: bias (+xproj for layer 0) + tanh, write h; h_final; out dot
        const int col = c0 + wrow;
        const float bv = (layer == 0) ? bias0[col] : bias1[col];
        float hv[4][4];
#pragma unroll
        for (int m = 0; m < 4; ++m) {
#pragma unroll
          for (int i = 0; i < 4; ++i) {
            const int brow = m * 16 + gg * 4 + i;
            float z = acc[m][i] + bv;
            if (layer == 0)
              z += xq[(size_t)(t & 3) * (Bz * Hz) + (size_t)brow * Hz + col];
            const float v = tanhf(z);
            hv[m][i] = v;
            hwr[((size_t)layer * Bz + brow) * Hz + col] = f2bf(v);
            if (t == Sz - 1)
              dout[Bz * Sz + ((size_t)layer * Bz + brow) * Hz + col] = v;
          }
        }
        if (layer == Lz - 1) {
          const float wov = wout[col];
#pragma unroll
          for (int m = 0; m < 4; ++m) {
#pragma unroll
            for (int i = 0; i < 4; ++i) {
              float pv = hv[m][i] * wov;
              pv += __shfl_xor(pv, 1);
              pv += __shfl_xor(pv, 2);
              pv += __shfl_xor(pv, 4);
              pv += __shfl_xor(pv, 8);
              if (cc == 0) {
                const int brow = m * 16 + gg * 4 + i;
                atomicAdd(&dout[(size_t)brow * Sz + t], pv);
              }
            }
          }
        }
      }
    } else {
      // ---- xproj crew: xq[tx&3] = x_tx @ W_ih^T (f32), register-direct, no barriers
      const int tx = w + 2;
      if (tx < Sz) {
        f32x4 acc[4];
#pragma unroll
        for (int m = 0; m < 4; ++m) acc[m] = (f32x4){0.f, 0.f, 0.f, 0.f};
#pragma unroll
        for (int step = 0; step < 8; ++step) {
#pragma unroll
          for (int ks = 0; ks < 2; ++ks) {
            const int k8g = step * 64 + ks * 32 + gg * 8;
            const bf16x8 bfrag = *(const bf16x8*)&Wlds[wrow * Iz + (k8g ^ xw)];
#pragma unroll
            for (int m = 0; m < 4; ++m) {
              const int ra = m * 16 + cc;
              const float* xs = x + ((size_t)ra * Sz + tx) * Iz + k8g;
              const float4 xa = *(const float4*)xs;
              const float4 xb = *(const float4*)(xs + 4);
              uint4 pv4;
              pv4.x = pkrnd(xa.x, xa.y);
              pv4.y = pkrnd(xa.z, xa.w);
              pv4.z = pkrnd(xb.x, xb.y);
              pv4.w = pkrnd(xb.z, xb.w);
              const bf16x8 afrag = *reinterpret_cast<const bf16x8*>(&pv4);
              acc[m] = __builtin_amdgcn_mfma_f32_16x16x32_bf16(afrag, bfrag, acc[m], 0, 0, 0);
            }
          }
        }
        float* xdst = xq + (size_t)(tx & 3) * (Bz * Hz);
        const int col = c0 + wrow;
#pragma unroll
        for (int m = 0; m < 4; ++m)
#pragma unroll
          for (int i = 0; i < 4; ++i)
            xdst[(size_t)(m * 16 + gg * 4 + i) * Hz + col] = acc[m][i];
      }
    }

    // ---- device-wide phase barrier (skip after final phase)
    if (w < Sz + Lz - 2) {
      __syncthreads();
      if (tid == 0) {
        __threadfence();
        __hip_atomic_fetch_add(cnt, 1, __ATOMIC_RELAXED, __HIP_MEMORY_SCOPE_AGENT);
        const int target = NB * (w + 3);
        while (__hip_atomic_load(cnt, __ATOMIC_RELAXED, __HIP_MEMORY_SCOPE_AGENT) < target) {
          __builtin_amdgcn_s_sleep(1);
        }
        __threadfence();
      }
      __syncthreads();
    }
  }
}

extern "C" void kernel_launch(void* const* d_in, const int* in_sizes, int n_in,
                              void* d_out, int out_size, void* d_ws, size_t ws_size,
                              hipStream_t stream) {
  (void)in_sizes; (void)n_in; (void)out_size; (void)ws_size;
  const float* x    = (const float*)d_in[0];
  const float* wih  = (const float*)d_in[1];
  const float* bih  = (const float*)d_in[2];
  const float* whh  = (const float*)d_in[3];
  const float* bhh  = (const float*)d_in[4];
  const float* wout = (const float*)d_in[5];
  const float* bout = (const float*)d_in[6];
  float* out = (float*)d_out;
  char* ws = (char*)d_ws;
  // ws: [0,1.5M) h dbl-buf bf16 | [1.5M,2.5M) xproj ring f32 [4][B][H] |
  //     [2.5M,+8K) bias0/bias1 | [2.5M+16K) sync counter
  unsigned short* hbuf = (unsigned short*)ws;
  float* xq    = (float*)(ws + ((size_t)3 << 19));
  float* bias0 = (float*)(ws + ((size_t)5 << 19));
  float* bias1 = bias0 + Hz;
  int* cnt     = (int*)(ws + ((size_t)5 << 19) + 16384);

  (void)hipFuncSetAttribute((const void*)rnn_kernel,
                            hipFuncAttributeMaxDynamicSharedMemorySize, 147456);
  (void)hipGetLastError();

  hipLaunchKernelGGL(init_kernel, dim3(256), dim3(256), 0, stream,
                     bih, bhh, bout, (unsigned int*)hbuf, bias0, bias1, out, cnt);
  hipLaunchKernelGGL(rnn_kernel, dim3(NB), dim3(256), 147456, stream,
                     x, wih, whh, wout, hbuf, xq, bias0, bias1, out, cnt);
}

// Round 3
// 7164.167 us; speedup vs baseline: 2.2729x; 2.2729x over previous
//
#include <hip/hip_runtime.h>

#define Bz 64
#define Sz 512
#define Iz 512
#define Hz 1024
#define Lz 6
#define NLWG 192   // 6 layers * 32 n-tiles of 32 cols
#define NWG 208    // + 16 xproj WGs (64 cols each)

typedef __attribute__((ext_vector_type(8))) short bf16x8;
typedef __attribute__((ext_vector_type(4))) float f32x4;

__device__ __forceinline__ unsigned short f2bf(float f) {
  unsigned u = __float_as_uint(f);
  u += 0x7fffu + ((u >> 16) & 1u);
  return (unsigned short)(u >> 16);
}
// pack two f32 -> bf16 pair (round-half-up, MFMA-input quality)
__device__ __forceinline__ unsigned pkrnd(float lo, float hi) {
  return ((__float_as_uint(lo) + 0x8000u) >> 16) |
         ((__float_as_uint(hi) + 0x8000u) & 0xffff0000u);
}

// Pre-swizzled bf16 weights: element (col,k) stored at [col][k ^ ((col&7)<<3)]
// so a LINEAR global_load_lds gives the XOR-swizzled LDS tile directly.
__global__ void init_kernel(const float* __restrict__ wih, const float* __restrict__ bih,
                            const float* __restrict__ whh, const float* __restrict__ bhh,
                            const float* __restrict__ bout,
                            unsigned short* __restrict__ Wbf,
                            unsigned short* __restrict__ Wihbf,
                            unsigned int* __restrict__ hbuf32,
                            float* __restrict__ bias0, float* __restrict__ bias1,
                            float* __restrict__ out) {
  int tid = blockIdx.x * blockDim.x + threadIdx.x;
  int nt = gridDim.x * blockDim.x;
  for (int i = tid; i < Hz * Hz; i += nt) {
    int col = i >> 10, k = i & 1023;
    Wbf[(col << 10) | (k ^ ((col & 7) << 3))] = f2bf(whh[i]);
  }
  for (int i = tid; i < Hz * Iz; i += nt) {
    int col = i >> 9, k = i & 511;
    Wihbf[(col << 9) | (k ^ ((col & 7) << 3))] = f2bf(wih[i]);
  }
  for (int i = tid; i < Lz * Bz * Hz; i += nt) hbuf32[i] = 0u;  // both h slots (u32 = 2 bf16)
  for (int i = tid; i < Hz; i += nt) {
    bias0[i] = bih[i] + bhh[i];   // layer 0
    bias1[i] = 2.0f * bhh[i];     // layers 1..5 (bias added twice in ref)
  }
  float b0 = bout[0];
  for (int i = tid; i < Bz * Sz; i += nt) out[i] = b0;
}

// K-loop: A operands gathered global->reg (6-deep ring), W from swizzled LDS.
template <bool DUAL>
__device__ __forceinline__ void kloop(const unsigned short* pA, const unsigned short* pB,
                                      const unsigned short* pW0, const unsigned short* pW1,
                                      int ksw0, int ksw1, f32x4& acc0, f32x4& acc1) {
  uint4 a1[6][2], a2[6][2];
#pragma unroll
  for (int c = 0; c < 5; ++c) {
    a1[c][0] = *(const uint4*)(pA + c * 64);
    a1[c][1] = *(const uint4*)(pA + c * 64 + 32);
    if (DUAL) {
      a2[c][0] = *(const uint4*)(pB + c * 64);
      a2[c][1] = *(const uint4*)(pB + c * 64 + 32);
    }
  }
#pragma unroll
  for (int c = 0; c < 16; ++c) {
    if (c + 5 < 16) {
      const int s = (c + 5) % 6;
      a1[s][0] = *(const uint4*)(pA + (c + 5) * 64);
      a1[s][1] = *(const uint4*)(pA + (c + 5) * 64 + 32);
      if (DUAL) {
        a2[s][0] = *(const uint4*)(pB + (c + 5) * 64);
        a2[s][1] = *(const uint4*)(pB + (c + 5) * 64 + 32);
      }
    }
    const int s = c % 6;
#pragma unroll
    for (int ks = 0; ks < 2; ++ks) {
      const int kof = c * 64 + (ks ? ksw1 : ksw0);
      const bf16x8 b0 = *(const bf16x8*)(pW0 + kof);
      const bf16x8 b1 = *(const bf16x8*)(pW1 + kof);
      const bf16x8 af1 = __builtin_bit_cast(bf16x8, a1[s][ks]);
      acc0 = __builtin_amdgcn_mfma_f32_16x16x32_bf16(af1, b0, acc0, 0, 0, 0);
      acc1 = __builtin_amdgcn_mfma_f32_16x16x32_bf16(af1, b1, acc1, 0, 0, 0);
      if (DUAL) {
        const bf16x8 af2 = __builtin_bit_cast(bf16x8, a2[s][ks]);
        acc0 = __builtin_amdgcn_mfma_f32_16x16x32_bf16(af2, b0, acc0, 0, 0, 0);
        acc1 = __builtin_amdgcn_mfma_f32_16x16x32_bf16(af2, b1, acc1, 0, 0, 0);
      }
    }
  }
}

__global__ __launch_bounds__(256) void phase_kernel(
    const float* __restrict__ x,
    const unsigned short* __restrict__ Wbf,
    const unsigned short* __restrict__ Wihbf,
    unsigned short* __restrict__ hbuf,
    float* __restrict__ xq,
    const float* __restrict__ bias0, const float* __restrict__ bias1,
    const float* __restrict__ wout,
    float* __restrict__ dout, int w) {
  extern __shared__ char lds[];
  const int tid = threadIdx.x;
  const int lane = tid & 63;
  const int wav = tid >> 6;
  const int cc = lane & 15;
  const int gg = lane >> 4;
  const int bid = blockIdx.x;

  if (bid < NLWG) {
    // layer-clustered bid->XCD mapping: g = (bid%8)*24 + bid/8 keeps each XCD on ~2 layers
    const int g = (bid & 7) * 24 + (bid >> 3);
    const int layer = g >> 5;
    const int t = w - layer;
    if (t < 0 || t >= Sz) return;
    const int c0 = (g & 31) << 5;  // 32 output cols
    unsigned short* Wl = (unsigned short*)lds;  // [32][1024] swizzled bf16

    // ---- stage W slice: linear copy of pre-swizzled bf16 (16B/lane)
    {
      const unsigned short* wsrc = Wbf + ((size_t)c0 << 10);
#pragma unroll
      for (int i = 0; i < 16; ++i) {
        const int off = (wav * 16 + i) * 512;
        __builtin_amdgcn_global_load_lds(wsrc + off + lane * 8, Wl + off, 16, 0, 0);
      }
    }

    const unsigned short* hrd = hbuf + (size_t)(w & 1) * (Lz * Bz * Hz);
    unsigned short* hwr = hbuf + (size_t)((w + 1) & 1) * (Lz * Bz * Hz);
    const int ra = wav * 16 + cc;  // A row (batch) this lane gathers
    const unsigned short* pA =
        hrd + ((size_t)((layer > 0 ? layer - 1 : 0) * Bz + ra)) * Hz + gg * 8;
    const unsigned short* pB = hrd + ((size_t)(layer * Bz + ra)) * Hz + gg * 8;

    const int ksw0 = (gg * 8) ^ ((cc & 7) << 3);
    const int ksw1 = (32 + gg * 8) ^ ((cc & 7) << 3);
    const unsigned short* pW0 = Wl + cc * 1024;         // n=0 col row
    const unsigned short* pW1 = Wl + (16 + cc) * 1024;  // n=1 col row

    asm volatile("s_waitcnt vmcnt(0)" ::: "memory");
    __builtin_amdgcn_s_barrier();
    __builtin_amdgcn_sched_barrier(0);

    f32x4 acc0 = {0.f, 0.f, 0.f, 0.f}, acc1 = {0.f, 0.f, 0.f, 0.f};
    if (layer == 0)
      kloop<false>(pA, pB, pW0, pW1, ksw0, ksw1, acc0, acc1);
    else
      kloop<true>(pA, pB, pW0, pW1, ksw0, ksw1, acc0, acc1);

    // ---- epilogue
    float hv[2][4];
#pragma unroll
    for (int n = 0; n < 2; ++n) {
      const int col = c0 + n * 16 + cc;
      const float bv = (layer == 0) ? bias0[col] : bias1[col];
      const f32x4 ac = n ? acc1 : acc0;
#pragma unroll
      for (int i = 0; i < 4; ++i) {
        const int brow = wav * 16 + gg * 4 + i;
        float z = ac[i] + bv;
        if (layer == 0)
          z += xq[(size_t)(t & 3) * (Bz * Hz) + (size_t)brow * Hz + col];
        const float v = tanhf(z);
        hv[n][i] = v;
        hwr[((size_t)layer * Bz + brow) * Hz + col] = f2bf(v);
        if (t == Sz - 1)
          dout[Bz * Sz + ((size_t)layer * Bz + brow) * Hz + col] = v;
      }
    }
    if (layer == Lz - 1) {
      const float wv0 = wout[c0 + cc];
      const float wv1 = wout[c0 + 16 + cc];
#pragma unroll
      for (int i = 0; i < 4; ++i) {
        float pv = hv[0][i] * wv0 + hv[1][i] * wv1;
        pv += __shfl_xor(pv, 1);
        pv += __shfl_xor(pv, 2);
        pv += __shfl_xor(pv, 4);
        pv += __shfl_xor(pv, 8);
        if (cc == 0) {
          const int brow = wav * 16 + gg * 4 + i;
          atomicAdd(&dout[(size_t)brow * Sz + t], pv);
        }
      }
    }
  } else {
    // ---- xproj crew: xq[(tx)&3] = x_tx @ W_ih^T (f32 accum), tx = w+2
    const int tx = w + 2;
    if (tx < 0 || tx >= Sz) return;
    const int xc0 = (bid - NLWG) << 6;                 // 64 cols
    unsigned short* Wxl = (unsigned short*)lds;        // [64][512] swizzled bf16
    float* xl = (float*)(lds + 65536);                 // 4 slots of [64][64] f32
    {
      const unsigned short* wsrc = Wihbf + ((size_t)xc0 << 9);
#pragma unroll
      for (int i = 0; i < 16; ++i) {
        const int off = (wav * 16 + i) * 512;
        __builtin_amdgcn_global_load_lds(wsrc + off + lane * 8, Wxl + off, 16, 0, 0);
      }
    }
    const int r4 = lane >> 4;
    const int qq = lane & 15;
    auto stage_x = [&](int c) {
      float* xs = xl + (size_t)(c & 3) * 4096;
#pragma unroll
      for (int j = 0; j < 4; ++j) {
        const int rb = wav * 16 + j * 4;
        const int row = rb + r4;
        const float* src =
            x + ((size_t)row * Sz + tx) * Iz + c * 64 + ((qq ^ (row & 7)) << 2);
        __builtin_amdgcn_global_load_lds(src, xs + rb * 64, 16, 0, 0);
      }
    };
    stage_x(0); stage_x(1); stage_x(2);
    const int ra = wav * 16 + cc;
    f32x4 acc[4];
#pragma unroll
    for (int n = 0; n < 4; ++n) acc[n] = (f32x4){0.f, 0.f, 0.f, 0.f};
#pragma unroll
    for (int c = 0; c < 8; ++c) {
      if (c <= 5)      asm volatile("s_waitcnt vmcnt(8)" ::: "memory");
      else if (c == 6) asm volatile("s_waitcnt vmcnt(4)" ::: "memory");
      else             asm volatile("s_waitcnt vmcnt(0)" ::: "memory");
      __builtin_amdgcn_s_barrier();
      __builtin_amdgcn_sched_barrier(0);
      if (c + 3 < 8) stage_x(c + 3);
      const float* xs = xl + (size_t)(c & 3) * 4096;
#pragma unroll
      for (int ks = 0; ks < 2; ++ks) {
        const int kq = ks * 8 + gg * 2;
        const f32x4 f0 = *(const f32x4*)(xs + ra * 64 + ((kq ^ (ra & 7)) << 2));
        const f32x4 f1 = *(const f32x4*)(xs + ra * 64 + (((kq + 1) ^ (ra & 7)) << 2));
        uint4 pk;
        pk.x = pkrnd(f0[0], f0[1]);
        pk.y = pkrnd(f0[2], f0[3]);
        pk.z = pkrnd(f1[0], f1[1]);
        pk.w = pkrnd(f1[2], f1[3]);
        const bf16x8 af = __builtin_bit_cast(bf16x8, pk);
        const int kof = c * 64 + ((ks * 32 + gg * 8) ^ ((cc & 7) << 3));
#pragma unroll
        for (int n = 0; n < 4; ++n) {
          const bf16x8 bf = *(const bf16x8*)(Wxl + (n * 16 + cc) * 512 + kof);
          acc[n] = __builtin_amdgcn_mfma_f32_16x16x32_bf16(af, bf, acc[n], 0, 0, 0);
        }
      }
    }
    float* xdst = xq + (size_t)(tx & 3) * (Bz * Hz);
#pragma unroll
    for (int n = 0; n < 4; ++n)
#pragma unroll
      for (int i = 0; i < 4; ++i) {
        const int brow = wav * 16 + gg * 4 + i;
        xdst[(size_t)brow * Hz + xc0 + n * 16 + cc] = acc[n][i];
      }
  }
}

extern "C" void kernel_launch(void* const* d_in, const int* in_sizes, int n_in,
                              void* d_out, int out_size, void* d_ws, size_t ws_size,
                              hipStream_t stream) {
  (void)in_sizes; (void)n_in; (void)out_size; (void)ws_size;
  const float* x    = (const float*)d_in[0];
  const float* wih  = (const float*)d_in[1];
  const float* bih  = (const float*)d_in[2];
  const float* whh  = (const float*)d_in[3];
  const float* bhh  = (const float*)d_in[4];
  const float* wout = (const float*)d_in[5];
  const float* bout = (const float*)d_in[6];
  float* out = (float*)d_out;
  char* ws = (char*)d_ws;
  // ws: [0,2M) Wbf | [2M,3M) Wihbf | [3M,4.5M) h dbl-buf bf16 |
  //     [4.5M,5.5M) xq ring f32[4][B][H] | [5.5M,+8K) bias0/bias1
  unsigned short* Wbf   = (unsigned short*)(ws);
  unsigned short* Wihbf = (unsigned short*)(ws + ((size_t)2 << 20));
  unsigned short* hbuf  = (unsigned short*)(ws + ((size_t)3 << 20));
  float* xq    = (float*)(ws + ((size_t)9 << 19));
  float* bias0 = (float*)(ws + ((size_t)11 << 19));
  float* bias1 = bias0 + Hz;

  (void)hipFuncSetAttribute((const void*)phase_kernel,
                            hipFuncAttributeMaxDynamicSharedMemorySize, 131072);
  (void)hipGetLastError();

  hipLaunchKernelGGL(init_kernel, dim3(1024), dim3(256), 0, stream,
                     wih, bih, whh, bhh, bout, Wbf, Wihbf,
                     (unsigned int*)hbuf, bias0, bias1, out);
  for (int w = -2; w <= Sz + Lz - 2; ++w) {
    hipLaunchKernelGGL(phase_kernel, dim3(NWG), dim3(256), 131072, stream,
                       x, Wbf, Wihbf, hbuf, xq, bias0, bias1, wout, out, w);
  }
}